// Round 1
// baseline (1625.705 us; speedup 1.0000x reference)
//
#include <hip/hip_runtime.h>

// ============================================================================
// R1 theory: 128^2 2-barrier GEMM sits at the m97-structure ceiling (~915 TF,
// MfmaUtil 39-41%). Bank conflicts already 0, HBM 44% -> not BW-bound; the
// stall is the per-K-step vmcnt(0)+barrier drain. Port to the 256^2 8-phase
// counted-vmcnt template (T1 XCD swizzle + T2 swizzled LDS + T3/T4 8-phase
// vmcnt(6) + T5 setprio) -> predict gemm ~600 -> ~380 us, MfmaUtil ~60%.
// ============================================================================

static constexpr int Mdim = 4096;
static constexpr int Kdim = 4096;
static constexpr int Ndim = 16384;

// ---- Path B (fallback) geometry ----
static constexpr int BM = 128, BN = 128, BK = 64;
static constexpr int TILES_N = Ndim / BN;  // 128
static constexpr int TILES_M = Mdim / BM;  // 32

// ---- Path A 8-phase geometry ----
static constexpr int BM2 = 256, BN2 = 256, BK2 = 64;
static constexpr int TM2 = Mdim / BM2;   // 16
static constexpr int TN2 = Ndim / BN2;   // 64
static constexpr int NT2 = Kdim / BK2;   // 64 K-tiles
static constexpr int NWG2 = TM2 * TN2;   // 1024 (% 8 == 0 -> simple XCD swizzle)

typedef __attribute__((ext_vector_type(8))) short bf16x8;  // 8 bf16 = 4 VGPRs
typedef __attribute__((ext_vector_type(4))) float f32x4;   // MFMA C/D

// ---------- conversion helpers ----------
__device__ __forceinline__ unsigned packbf(float lo, float hi) {
  unsigned a = __builtin_bit_cast(unsigned, lo);
  unsigned b = __builtin_bit_cast(unsigned, hi);
  a += 0x7FFFu + ((a >> 16) & 1u);
  b += 0x7FFFu + ((b >> 16) & 1u);
  return (a >> 16) | (b & 0xFFFF0000u);
}

__device__ __forceinline__ unsigned i32x2bf(int lo, int hi) {
  float f0 = (float)lo;
  float f1 = (float)hi;
  return (__builtin_bit_cast(unsigned, f0) >> 16) |
         (__builtin_bit_cast(unsigned, f1) & 0xFFFF0000u);
}

// ---------- standalone converters (memory-bound) ----------
__global__ void cvt_x_kernel(const float4* __restrict__ in, uint4* __restrict__ out) {
  int i = blockIdx.x * 256 + threadIdx.x;
  float4 a = in[2 * i];
  float4 b = in[2 * i + 1];
  uint4 o;
  o.x = packbf(a.x, a.y);
  o.y = packbf(a.z, a.w);
  o.z = packbf(b.x, b.y);
  o.w = packbf(b.z, b.w);
  out[i] = o;
}

// harness uploads integer inputs as int32: weight_q is N*K int32 in [-127,127].
__global__ void cvt_w_kernel(const int4* __restrict__ in, uint4* __restrict__ out) {
  int i = blockIdx.x * 256 + threadIdx.x;
  int4 a = in[2 * i];
  int4 b = in[2 * i + 1];
  uint4 o;
  o.x = i32x2bf(a.x, a.y);
  o.y = i32x2bf(a.z, a.w);
  o.z = i32x2bf(b.x, b.y);
  o.w = i32x2bf(b.z, b.w);
  out[i] = o;
}

// ============================================================================
// Path A GEMM: 256x256 tile, BK=64, 8 waves (2M x 4N), 8-phase counted-vmcnt.
//
// LDS (128 KiB): As/Bs each [buf:2][half:2][1024 chunks][8 bf16].
//   A half h covers tile rows {0-63,128-191} (h=0) / {64-127,192-255} (h=1)
//   so a half == exactly the rows whose ds_reads retire in one phase pair.
//   B half h covers rows h*128..h*128+127 (each wave reads ONE B half).
//   Chunk (row ir, k-chunk c) stored at slot ir*8 + (c ^ (ir&7)) -- the
//   measured zero-conflict swizzle; staging writes slots linearly via
//   global_load_lds with the INVERSE swizzle applied to the global source
//   (both-sides rule). One half-tile = 16 chunk-rows of 64 chunks = 8 waves
//   x 2 global_load_lds (1 KiB per wave per instruction).
//
// Schedule (group g reads tile g from buf d=g&1; 4 phases per group):
//   ph0: ds_read A(h0) 8x + B(n0,1) 4x | stage tile g+1 A(h1) -> buf d^1
//        | bar; lgkm0; prio1; 16 MFMA acc[0..3][0..1]; prio0; bar
//   ph1: ds_read B(n2,3) 4x           | stage tile g+2 A(h0) -> buf d
//   ph2: ds_read A(h1) 8x             | stage tile g+2 B(h0) -> buf d
//   ph3: (no reads)                   | stage tile g+2 B(h1) -> buf d
//        | bar; prio1; 16 MFMA; prio0; vmcnt(6); bar
//   Region safety: a stage into buf d targets only regions whose last
//   ds_read completed a phase earlier (lgkm0 precedes that phase's closing
//   barrier). vmcnt(6) leaves exactly the newest 3 half-tiles (tile g+2's
//   A0,B0,B1) in flight; everything needed by group g+1 has landed.
// ============================================================================

__global__ __launch_bounds__(512, 2) void gemm_bf16_8ph(
    const unsigned short* __restrict__ A,   // [M,K] bf16
    const unsigned short* __restrict__ B,   // [N,K] bf16
    const float* __restrict__ scale,
    const float* __restrict__ bias,
    float* __restrict__ out) {
  __shared__ unsigned short As[2 * 2 * 1024 * 8];  // 64 KiB
  __shared__ unsigned short Bs[2 * 2 * 1024 * 8];  // 64 KiB

  const int tid = threadIdx.x;
  const int lane = tid & 63;
  const int w = tid >> 6;           // wave 0..7
  const int wm = w >> 2;            // 0..1 -> rows wm*128
  const int wn = w & 3;             // 0..3 -> cols wn*64
  const int l15 = lane & 15;
  const int quad = lane >> 4;
  const int sw = l15 & 7;           // read-side swizzle key
  const int bhalf = wn >> 1;        // this wave's fixed B half

  // T1: bijective XCD swizzle (NWG2 % 8 == 0)
  const int bid = blockIdx.x;
  const int wg = (bid & 7) * (NWG2 / 8) + (bid >> 3);
  const int bm = wg / TN2, bn = wg % TN2;
  const int row0 = bm * BM2, col0 = bn * BN2;

  // Per-thread pre-swizzled global byte offsets for staging, [half][load i].
  unsigned aoff[2][2], boff[2][2];
#pragma unroll
  for (int h = 0; h < 2; ++h)
#pragma unroll
    for (int i = 0; i < 2; ++i) {
      int ch = (w * 2 + i) * 64 + lane;       // chunk within half-tile
      int ir = ch >> 3;                        // inner row 0..127
      int c = (ch & 7) ^ (ir & 7);             // inverse of read swizzle
      int ra = (ir >> 6) * 128 + h * 64 + (ir & 63);  // A tile row
      int rb = h * 128 + ir;                           // B tile row
      aoff[h][i] = (unsigned)((((long)(row0 + ra)) * Kdim + c * 8) * 2);
      boff[h][i] = (unsigned)((((long)(col0 + rb)) * Kdim + c * 8) * 2);
    }

#define STG_A(d, h, kt)                                                                   \
  do {                                                                                    \
    __builtin_amdgcn_global_load_lds(                                                     \
        (const __attribute__((address_space(1))) void*)((const char*)A + aoff[h][0] + (kt)*128), \
        (__attribute__((address_space(3))) void*)(&As[(((d)*2 + (h)) * 1024 + (w*2 + 0) * 64) * 8]), 16, 0, 0); \
    __builtin_amdgcn_global_load_lds(                                                     \
        (const __attribute__((address_space(1))) void*)((const char*)A + aoff[h][1] + (kt)*128), \
        (__attribute__((address_space(3))) void*)(&As[(((d)*2 + (h)) * 1024 + (w*2 + 1) * 64) * 8]), 16, 0, 0); \
  } while (0)

#define STG_B(d, h, kt)                                                                   \
  do {                                                                                    \
    __builtin_amdgcn_global_load_lds(                                                     \
        (const __attribute__((address_space(1))) void*)((const char*)B + boff[h][0] + (kt)*128), \
        (__attribute__((address_space(3))) void*)(&Bs[(((d)*2 + (h)) * 1024 + (w*2 + 0) * 64) * 8]), 16, 0, 0); \
    __builtin_amdgcn_global_load_lds(                                                     \
        (const __attribute__((address_space(1))) void*)((const char*)B + boff[h][1] + (kt)*128), \
        (__attribute__((address_space(3))) void*)(&Bs[(((d)*2 + (h)) * 1024 + (w*2 + 1) * 64) * 8]), 16, 0, 0); \
  } while (0)

// Fragment reads (swizzled).  A: half h, m-subtile t3 (0..3).  B: n-subtile n.
#define LDA(dst, d, h, t3, ks)                                                            \
  dst = *(const bf16x8*)(As + ((((d)*2 + (h)) * 1024 + (wm * 64 + (t3) * 16 + l15) * 8 +  \
                                (((ks)*4 + quad) ^ sw)) * 8))
#define LDB(dst, d, n, ks)                                                                \
  dst = *(const bf16x8*)(Bs + ((((d)*2 + bhalf) * 1024 + ((wn & 1) * 64 + (n) * 16 + l15) * 8 + \
                                (((ks)*4 + quad) ^ sw)) * 8))

  f32x4 acc[8][4];
#pragma unroll
  for (int mi = 0; mi < 8; ++mi)
#pragma unroll
    for (int ni = 0; ni < 4; ++ni) acc[mi][ni] = (f32x4){0.f, 0.f, 0.f, 0.f};

  bf16x8 af[4][2];  // current A half (reused h0 -> h1)
  bf16x8 bf[4][2];  // all 4 n-subtiles of this wave's B half

  auto GROUP = [&](int g, int d, bool s1, bool s2) {
    const int dn = d ^ 1;
    // ---- phase 0: A(h0) + B(n0,1); stage tile g+1 A(h1) ----
#pragma unroll
    for (int t = 0; t < 4; ++t) {
      LDA(af[t][0], d, 0, t, 0);
      LDA(af[t][1], d, 0, t, 1);
    }
#pragma unroll
    for (int n = 0; n < 2; ++n) {
      LDB(bf[n][0], d, n, 0);
      LDB(bf[n][1], d, n, 1);
    }
    if (s1) STG_A(dn, 1, g + 1);
    __builtin_amdgcn_s_barrier();
    asm volatile("s_waitcnt lgkmcnt(0)" ::: "memory");
    __builtin_amdgcn_s_setprio(1);
#pragma unroll
    for (int mi = 0; mi < 4; ++mi)
#pragma unroll
      for (int ni = 0; ni < 2; ++ni)
#pragma unroll
        for (int ks = 0; ks < 2; ++ks)
          acc[mi][ni] = __builtin_amdgcn_mfma_f32_16x16x32_bf16(af[mi][ks], bf[ni][ks], acc[mi][ni], 0, 0, 0);
    __builtin_amdgcn_s_setprio(0);
    __builtin_amdgcn_s_barrier();

    // ---- phase 1: B(n2,3); stage tile g+2 A(h0) ----
#pragma unroll
    for (int n = 0; n < 2; ++n) {
      LDB(bf[2 + n][0], d, 2 + n, 0);
      LDB(bf[2 + n][1], d, 2 + n, 1);
    }
    if (s2) STG_A(d, 0, g + 2);
    __builtin_amdgcn_s_barrier();
    asm volatile("s_waitcnt lgkmcnt(0)" ::: "memory");
    __builtin_amdgcn_s_setprio(1);
#pragma unroll
    for (int mi = 0; mi < 4; ++mi)
#pragma unroll
      for (int ni = 0; ni < 2; ++ni)
#pragma unroll
        for (int ks = 0; ks < 2; ++ks)
          acc[mi][2 + ni] = __builtin_amdgcn_mfma_f32_16x16x32_bf16(af[mi][ks], bf[2 + ni][ks], acc[mi][2 + ni], 0, 0, 0);
    __builtin_amdgcn_s_setprio(0);
    __builtin_amdgcn_s_barrier();

    // ---- phase 2: A(h1); stage tile g+2 B(h0) ----
#pragma unroll
    for (int t = 0; t < 4; ++t) {
      LDA(af[t][0], d, 1, t, 0);
      LDA(af[t][1], d, 1, t, 1);
    }
    if (s2) STG_B(d, 0, g + 2);
    __builtin_amdgcn_s_barrier();
    asm volatile("s_waitcnt lgkmcnt(0)" ::: "memory");
    __builtin_amdgcn_s_setprio(1);
#pragma unroll
    for (int mi = 0; mi < 4; ++mi)
#pragma unroll
      for (int ni = 0; ni < 2; ++ni)
#pragma unroll
        for (int ks = 0; ks < 2; ++ks)
          acc[4 + mi][ni] = __builtin_amdgcn_mfma_f32_16x16x32_bf16(af[mi][ks], bf[ni][ks], acc[4 + mi][ni], 0, 0, 0);
    __builtin_amdgcn_s_setprio(0);
    __builtin_amdgcn_s_barrier();

    // ---- phase 3: no reads; stage tile g+2 B(h1); counted vmcnt at end ----
    if (s2) STG_B(d, 1, g + 2);
    __builtin_amdgcn_s_barrier();
    __builtin_amdgcn_s_setprio(1);
#pragma unroll
    for (int mi = 0; mi < 4; ++mi)
#pragma unroll
      for (int ni = 0; ni < 2; ++ni)
#pragma unroll
        for (int ks = 0; ks < 2; ++ks)
          acc[4 + mi][2 + ni] = __builtin_amdgcn_mfma_f32_16x16x32_bf16(af[mi][ks], bf[2 + ni][ks], acc[4 + mi][2 + ni], 0, 0, 0);
    __builtin_amdgcn_s_setprio(0);
    asm volatile("s_waitcnt vmcnt(6)" ::: "memory");  // newest 3 half-tiles stay in flight
    __builtin_amdgcn_s_barrier();
  };

  // Prologue: tile0 fully + tile1 {A0,B0,B1}; tile1's A1 comes from group 0 ph0.
  STG_A(0, 0, 0);
  STG_A(0, 1, 0);
  STG_B(0, 0, 0);
  STG_B(0, 1, 0);
  STG_A(1, 0, 1);
  STG_B(1, 0, 1);
  STG_B(1, 1, 1);
  asm volatile("s_waitcnt vmcnt(6)" ::: "memory");  // tile0 resident; tile1 in flight
  __builtin_amdgcn_s_barrier();

#pragma unroll 1
  for (int g = 0; g < NT2 - 2; g += 2) {
    GROUP(g, 0, true, true);
    GROUP(g + 1, 1, true, true);
  }
  GROUP(NT2 - 2, 0, true, false);
  // Tail: pipeline no longer pushes old loads past the vmcnt(6) window ->
  // full drain before the last group's reads.
  asm volatile("s_waitcnt vmcnt(0)" ::: "memory");
  __builtin_amdgcn_s_barrier();
  GROUP(NT2 - 1, 1, false, false);

#undef STG_A
#undef STG_B
#undef LDA
#undef LDB

  // Epilogue: C/D layout col=lane&15, row=quad*4+reg (m89-verified).
  const int rbase = quad * 4;
#pragma unroll
  for (int ni = 0; ni < 4; ++ni) {
    const int n = col0 + wn * 64 + ni * 16 + l15;
    const float sc = scale[n];
    const float bz = bias[n];
#pragma unroll
    for (int mi = 0; mi < 8; ++mi) {
      const int m = row0 + wm * 128 + mi * 16 + rbase;
      float* o = out + (long)m * Ndim + n;
#pragma unroll
      for (int r = 0; r < 4; ++r) o[(long)r * Ndim] = acc[mi][ni][r] * sc + bz;
    }
  }
}

// ============================================================================
// Path B fallback (fused conversion, 128^2) -- unchanged from previous round.
// ============================================================================
__device__ __forceinline__ void mfma_tile(const unsigned short* As, const unsigned short* Bs,
                                          int am, int bnl, int quad, f32x4 acc[4][4]) {
#pragma unroll
  for (int ks = 0; ks < 2; ++ks) {
    const int c = ks * 4 + quad;
    bf16x8 af[4], bv[4];
#pragma unroll
    for (int t = 0; t < 4; ++t) {
      int ma = am + t * 16;
      af[t] = *(const bf16x8*)(As + (ma * 8 + (c ^ (ma & 7))) * 8);
      int nb = bnl + t * 16;
      bv[t] = *(const bf16x8*)(Bs + (nb * 8 + (c ^ (nb & 7))) * 8);
    }
#pragma unroll
    for (int mi = 0; mi < 4; ++mi)
#pragma unroll
      for (int ni = 0; ni < 4; ++ni)
        acc[mi][ni] = __builtin_amdgcn_mfma_f32_16x16x32_bf16(af[mi], bv[ni], acc[mi][ni], 0, 0, 0);
  }
}

__device__ __forceinline__ void epilogue128(float* __restrict__ out,
                                            const float* __restrict__ scale,
                                            const float* __restrict__ bias,
                                            int row0, int col0, int wm, int wn, int lane,
                                            f32x4 acc[4][4]) {
  const int rbase = (lane >> 4) * 4;
#pragma unroll
  for (int ni = 0; ni < 4; ++ni) {
    const int n = col0 + wn * 64 + ni * 16 + (lane & 15);
    const float sc = scale[n];
    const float bz = bias[n];
#pragma unroll
    for (int mi = 0; mi < 4; ++mi) {
      const int m = row0 + wm * 64 + mi * 16 + rbase;
      float* o = out + (long)m * Ndim + n;
#pragma unroll
      for (int r = 0; r < 4; ++r)
        o[(long)r * Ndim] = acc[mi][ni][r] * sc + bz;
    }
  }
}

__global__ __launch_bounds__(256, 2) void gemm_fused(const float* __restrict__ X,
                                                     const int* __restrict__ Wq,
                                                     const float* __restrict__ scale,
                                                     const float* __restrict__ bias,
                                                     float* __restrict__ out) {
  __shared__ unsigned short As[BM * BK];
  __shared__ unsigned short Bs[BN * BK];

  const int tid = threadIdx.x;
  const int lane = tid & 63;
  const int w = tid >> 6;
  const int wm = w & 1, wn = w >> 1;
  const int bid = blockIdx.x;
  const int bn = bid % TILES_N;
  const int bm = bid / TILES_N;
  const int row0 = bm * BM, col0 = bn * BN;

  int slot[4];
  long aoff[4], boff[4];
#pragma unroll
  for (int i = 0; i < 4; ++i) {
    int s = i * 256 + tid;
    int m = s >> 3, cs = s & 7, c = cs ^ (m & 7);
    slot[i] = s;
    aoff[i] = (long)(row0 + m) * Kdim + c * 8;
    boff[i] = (long)(col0 + m) * Kdim + c * 8;
  }

  f32x4 acc[4][4];
#pragma unroll
  for (int mi = 0; mi < 4; ++mi)
#pragma unroll
    for (int ni = 0; ni < 4; ++ni) acc[mi][ni] = (f32x4){0.f, 0.f, 0.f, 0.f};

  const int am = wm * 64 + (lane & 15);
  const int bnl = wn * 64 + (lane & 15);
  const int quad = lane >> 4;

  for (int kt = 0; kt < Kdim / BK; ++kt) {
    uint4 aw[4], bw[4];
#pragma unroll
    for (int i = 0; i < 4; ++i) {
      const float4* ap = (const float4*)(X + aoff[i] + kt * BK);
      float4 a0 = ap[0];
      float4 a1 = ap[1];
      aw[i].x = packbf(a0.x, a0.y);
      aw[i].y = packbf(a0.z, a0.w);
      aw[i].z = packbf(a1.x, a1.y);
      aw[i].w = packbf(a1.z, a1.w);
      const int4* bp = (const int4*)(Wq + boff[i] + kt * BK);
      int4 b0 = bp[0];
      int4 b1 = bp[1];
      bw[i].x = i32x2bf(b0.x, b0.y);
      bw[i].y = i32x2bf(b0.z, b0.w);
      bw[i].z = i32x2bf(b1.x, b1.y);
      bw[i].w = i32x2bf(b1.z, b1.w);
    }
    __syncthreads();
#pragma unroll
    for (int i = 0; i < 4; ++i) {
      *(uint4*)(&As[slot[i] * 8]) = aw[i];
      *(uint4*)(&Bs[slot[i] * 8]) = bw[i];
    }
    __syncthreads();
    mfma_tile(As, Bs, am, bnl, quad, acc);
  }
  epilogue128(out, scale, bias, row0, col0, wm, wn, lane, acc);
}

extern "C" void kernel_launch(void* const* d_in, const int* in_sizes, int n_in,
                              void* d_out, int out_size, void* d_ws, size_t ws_size,
                              hipStream_t stream) {
  const float* x = (const float*)d_in[0];
  const int* wq = (const int*)d_in[1];      // int8 weights uploaded as int32 [N*K]
  const float* wscale = (const float*)d_in[2];
  const float* wbias = (const float*)d_in[3];
  float* out = (float*)d_out;

  const size_t needA = ((size_t)Mdim * Kdim + (size_t)Ndim * Kdim) * 2;  // 160 MB bf16
  if (ws_size >= needA) {
    unsigned short* xb = (unsigned short*)d_ws;
    unsigned short* wb = xb + (size_t)Mdim * Kdim;
    cvt_x_kernel<<<(Mdim * Kdim) / 8 / 256, 256, 0, stream>>>((const float4*)x, (uint4*)xb);
    cvt_w_kernel<<<(Ndim / 256) * (Kdim / 8), 256, 0, stream>>>((const int4*)wq, (uint4*)wb);
    gemm_bf16_8ph<<<NWG2, 512, 0, stream>>>(xb, wb, wscale, wbias, out);
  } else {
    gemm_fused<<<TILES_M * TILES_N, 256, 0, stream>>>(x, wq, wscale, wbias, out);
  }
}

// Round 2
// 1471.606 us; speedup vs baseline: 1.1047x; 1.1047x over previous
//
#include <hip/hip_runtime.h>

// ============================================================================
// R2 theory: R1's 8-phase port collapsed (1220us, MfmaUtil 17%, VGPR=128,
// WRITE_SIZE +56MB) because the GROUP lambda (64 MFMA + 24 ds_read + 8
// global_load_lds body, 4 call sites) was NOT inlined -> by-ref captures
// forced acc/af/bf to scratch -> every MFMA became scratch RMW.
// Fix: identical schedule, group body as macro (guaranteed textual inline,
// literal d/s1/s2). Predict gemm ~1220 -> ~360-430us, MfmaUtil ~55-62%,
// VGPR ~190-250, WRITE_SIZE back to ~290MB.
// ============================================================================

static constexpr int Mdim = 4096;
static constexpr int Kdim = 4096;
static constexpr int Ndim = 16384;

// ---- Path B (fallback) geometry ----
static constexpr int BM = 128, BN = 128, BK = 64;
static constexpr int TILES_N = Ndim / BN;  // 128
static constexpr int TILES_M = Mdim / BM;  // 32

// ---- Path A 8-phase geometry ----
static constexpr int BM2 = 256, BN2 = 256, BK2 = 64;
static constexpr int TM2 = Mdim / BM2;   // 16
static constexpr int TN2 = Ndim / BN2;   // 64
static constexpr int NT2 = Kdim / BK2;   // 64 K-tiles
static constexpr int NWG2 = TM2 * TN2;   // 1024 (% 8 == 0 -> simple XCD swizzle)

typedef __attribute__((ext_vector_type(8))) short bf16x8;  // 8 bf16 = 4 VGPRs
typedef __attribute__((ext_vector_type(4))) float f32x4;   // MFMA C/D

// ---------- conversion helpers ----------
__device__ __forceinline__ unsigned packbf(float lo, float hi) {
  unsigned a = __builtin_bit_cast(unsigned, lo);
  unsigned b = __builtin_bit_cast(unsigned, hi);
  a += 0x7FFFu + ((a >> 16) & 1u);
  b += 0x7FFFu + ((b >> 16) & 1u);
  return (a >> 16) | (b & 0xFFFF0000u);
}

__device__ __forceinline__ unsigned i32x2bf(int lo, int hi) {
  float f0 = (float)lo;
  float f1 = (float)hi;
  return (__builtin_bit_cast(unsigned, f0) >> 16) |
         (__builtin_bit_cast(unsigned, f1) & 0xFFFF0000u);
}

// ---------- standalone converters (memory-bound) ----------
__global__ void cvt_x_kernel(const float4* __restrict__ in, uint4* __restrict__ out) {
  int i = blockIdx.x * 256 + threadIdx.x;
  float4 a = in[2 * i];
  float4 b = in[2 * i + 1];
  uint4 o;
  o.x = packbf(a.x, a.y);
  o.y = packbf(a.z, a.w);
  o.z = packbf(b.x, b.y);
  o.w = packbf(b.z, b.w);
  out[i] = o;
}

// harness uploads integer inputs as int32: weight_q is N*K int32 in [-127,127].
__global__ void cvt_w_kernel(const int4* __restrict__ in, uint4* __restrict__ out) {
  int i = blockIdx.x * 256 + threadIdx.x;
  int4 a = in[2 * i];
  int4 b = in[2 * i + 1];
  uint4 o;
  o.x = i32x2bf(a.x, a.y);
  o.y = i32x2bf(a.z, a.w);
  o.z = i32x2bf(b.x, b.y);
  o.w = i32x2bf(b.z, b.w);
  out[i] = o;
}

// ============================================================================
// Path A GEMM: 256x256 tile, BK=64, 8 waves (2M x 4N), 8-phase counted-vmcnt.
// Schedule identical to R1 (analysis in that round's comment); group body is
// now a macro so d/s1/s2 are literals and all state stays in registers.
// ============================================================================

__global__ __launch_bounds__(512, 2) void gemm_bf16_8ph(
    const unsigned short* __restrict__ A,   // [M,K] bf16
    const unsigned short* __restrict__ B,   // [N,K] bf16
    const float* __restrict__ scale,
    const float* __restrict__ bias,
    float* __restrict__ out) {
  __shared__ unsigned short As[2 * 2 * 1024 * 8];  // 64 KiB
  __shared__ unsigned short Bs[2 * 2 * 1024 * 8];  // 64 KiB

  const int tid = threadIdx.x;
  const int lane = tid & 63;
  const int w = tid >> 6;           // wave 0..7
  const int wm = w >> 2;            // 0..1 -> rows wm*128
  const int wn = w & 3;             // 0..3 -> cols wn*64
  const int l15 = lane & 15;
  const int quad = lane >> 4;
  const int sw = l15 & 7;           // read-side swizzle key
  const int bhalf = wn >> 1;        // this wave's fixed B half

  // T1: bijective XCD swizzle (NWG2 % 8 == 0)
  const int bid = blockIdx.x;
  const int wg = (bid & 7) * (NWG2 / 8) + (bid >> 3);
  const int bm = wg / TN2, bn = wg % TN2;
  const int row0 = bm * BM2, col0 = bn * BN2;

  // Per-thread pre-swizzled global byte offsets for staging, [half][load i].
  unsigned aoff[2][2], boff[2][2];
#pragma unroll
  for (int h = 0; h < 2; ++h)
#pragma unroll
    for (int i = 0; i < 2; ++i) {
      int ch = (w * 2 + i) * 64 + lane;       // chunk within half-tile
      int ir = ch >> 3;                        // inner row 0..127
      int c = (ch & 7) ^ (ir & 7);             // inverse of read swizzle
      int ra = (ir >> 6) * 128 + h * 64 + (ir & 63);  // A tile row
      int rb = h * 128 + ir;                           // B tile row
      aoff[h][i] = (unsigned)((((long)(row0 + ra)) * Kdim + c * 8) * 2);
      boff[h][i] = (unsigned)((((long)(col0 + rb)) * Kdim + c * 8) * 2);
    }

#define STG_A(d, h, kt)                                                                   \
  do {                                                                                    \
    __builtin_amdgcn_global_load_lds(                                                     \
        (const __attribute__((address_space(1))) void*)((const char*)A + aoff[h][0] + (kt)*128), \
        (__attribute__((address_space(3))) void*)(&As[(((d)*2 + (h)) * 1024 + (w*2 + 0) * 64) * 8]), 16, 0, 0); \
    __builtin_amdgcn_global_load_lds(                                                     \
        (const __attribute__((address_space(1))) void*)((const char*)A + aoff[h][1] + (kt)*128), \
        (__attribute__((address_space(3))) void*)(&As[(((d)*2 + (h)) * 1024 + (w*2 + 1) * 64) * 8]), 16, 0, 0); \
  } while (0)

#define STG_B(d, h, kt)                                                                   \
  do {                                                                                    \
    __builtin_amdgcn_global_load_lds(                                                     \
        (const __attribute__((address_space(1))) void*)((const char*)B + boff[h][0] + (kt)*128), \
        (__attribute__((address_space(3))) void*)(&Bs[(((d)*2 + (h)) * 1024 + (w*2 + 0) * 64) * 8]), 16, 0, 0); \
    __builtin_amdgcn_global_load_lds(                                                     \
        (const __attribute__((address_space(1))) void*)((const char*)B + boff[h][1] + (kt)*128), \
        (__attribute__((address_space(3))) void*)(&Bs[(((d)*2 + (h)) * 1024 + (w*2 + 1) * 64) * 8]), 16, 0, 0); \
  } while (0)

// Fragment reads (swizzled).  A: half h, m-subtile t3 (0..3).  B: n-subtile n.
#define LDA(dst, d, h, t3, ks)                                                            \
  dst = *(const bf16x8*)(As + ((((d)*2 + (h)) * 1024 + (wm * 64 + (t3) * 16 + l15) * 8 +  \
                                (((ks)*4 + quad) ^ sw)) * 8))
#define LDB(dst, d, n, ks)                                                                \
  dst = *(const bf16x8*)(Bs + ((((d)*2 + bhalf) * 1024 + ((wn & 1) * 64 + (n) * 16 + l15) * 8 + \
                                (((ks)*4 + quad) ^ sw)) * 8))

#define LDA8(d, h)                                                                        \
  _Pragma("unroll") for (int t = 0; t < 4; ++t) {                                         \
    LDA(af[t][0], d, h, t, 0);                                                            \
    LDA(af[t][1], d, h, t, 1);                                                            \
  }

#define LDB4(d, n0)                                                                       \
  _Pragma("unroll") for (int n = 0; n < 2; ++n) {                                         \
    LDB(bf[(n0) + n][0], d, (n0) + n, 0);                                                 \
    LDB(bf[(n0) + n][1], d, (n0) + n, 1);                                                 \
  }

#define MFMAQ(mb, nb)                                                                     \
  __builtin_amdgcn_s_setprio(1);                                                          \
  _Pragma("unroll") for (int mi = 0; mi < 4; ++mi) {                                      \
    _Pragma("unroll") for (int ni = 0; ni < 2; ++ni) {                                    \
      _Pragma("unroll") for (int ks = 0; ks < 2; ++ks) {                                  \
        acc[(mb) + mi][(nb) + ni] = __builtin_amdgcn_mfma_f32_16x16x32_bf16(              \
            af[mi][ks], bf[(nb) + ni][ks], acc[(mb) + mi][(nb) + ni], 0, 0, 0);           \
      }                                                                                   \
    }                                                                                     \
  }                                                                                       \
  __builtin_amdgcn_s_setprio(0);

#define BAR __builtin_amdgcn_s_barrier()
#define LGKM0 asm volatile("s_waitcnt lgkmcnt(0)" ::: "memory")
#define VMC(n) asm volatile("s_waitcnt vmcnt(" #n ")" ::: "memory")

// One K-tile (4 phases). d/dn/S1/S2 MUST be literal constants.
//   ph0: LDA h0 + LDB n0,1 | stage tile g+1 A(h1)->buf dn | bar,lgkm0,MFMA q00
//   ph1: LDB n2,3          | stage tile g+2 A(h0)->buf d  | bar,lgkm0,MFMA q01
//   ph2: LDA h1            | stage tile g+2 B(h0)->buf d  | bar,lgkm0,MFMA q10
//   ph3:                   | stage tile g+2 B(h1)->buf d  | bar,MFMA q11,vmcnt(6)
// vmcnt(6) leaves exactly tile g+2's {A0,B0,B1} (newest 3 half-tiles) in
// flight; everything group g+1 reads has landed. WAR safety: each stage into a
// region is >=1 full barrier after that region's last ds_read completed.
#define GROUP(g, d, dn, S1, S2)              \
  {                                          \
    LDA8(d, 0);                              \
    LDB4(d, 0);                              \
    if (S1) STG_A(dn, 1, (g) + 1);           \
    BAR;                                     \
    LGKM0;                                   \
    MFMAQ(0, 0);                             \
    BAR;                                     \
    LDB4(d, 2);                              \
    if (S2) STG_A(d, 0, (g) + 2);            \
    BAR;                                     \
    LGKM0;                                   \
    MFMAQ(0, 2);                             \
    BAR;                                     \
    LDA8(d, 1);                              \
    if (S2) STG_B(d, 0, (g) + 2);            \
    BAR;                                     \
    LGKM0;                                   \
    MFMAQ(4, 0);                             \
    BAR;                                     \
    if (S2) STG_B(d, 1, (g) + 2);            \
    BAR;                                     \
    MFMAQ(4, 2);                             \
    VMC(6);                                  \
    BAR;                                     \
  }

  f32x4 acc[8][4];
#pragma unroll
  for (int mi = 0; mi < 8; ++mi)
#pragma unroll
    for (int ni = 0; ni < 4; ++ni) acc[mi][ni] = (f32x4){0.f, 0.f, 0.f, 0.f};

  bf16x8 af[4][2];  // current A half (reused h0 -> h1)
  bf16x8 bf[4][2];  // all 4 n-subtiles of this wave's B half

  // Prologue: tile0 fully + tile1 {A0,B0,B1}; tile1's A1 comes from group 0 ph0.
  STG_A(0, 0, 0);
  STG_A(0, 1, 0);
  STG_B(0, 0, 0);
  STG_B(0, 1, 0);
  STG_A(1, 0, 1);
  STG_B(1, 0, 1);
  STG_B(1, 1, 1);
  VMC(6);  // tile0 resident; tile1's 3 half-tiles stay in flight
  BAR;

#pragma unroll 1
  for (int g = 0; g < NT2 - 2; g += 2) {
    GROUP(g, 0, 1, 1, 1);
    GROUP(g + 1, 1, 0, 1, 1);
  }
  GROUP(NT2 - 2, 0, 1, 1, 0);
  // Tail: drain everything before the final tile's reads.
  VMC(0);
  BAR;
  GROUP(NT2 - 1, 1, 0, 0, 0);

#undef GROUP
#undef STG_A
#undef STG_B
#undef LDA
#undef LDB
#undef LDA8
#undef LDB4
#undef MFMAQ

  // Epilogue: C/D layout col=lane&15, row=quad*4+reg (m89-verified).
  const int rbase = quad * 4;
#pragma unroll
  for (int ni = 0; ni < 4; ++ni) {
    const int n = col0 + wn * 64 + ni * 16 + l15;
    const float sc = scale[n];
    const float bz = bias[n];
#pragma unroll
    for (int mi = 0; mi < 8; ++mi) {
      const int m = row0 + wm * 128 + mi * 16 + rbase;
      float* o = out + (long)m * Ndim + n;
#pragma unroll
      for (int r = 0; r < 4; ++r) o[(long)r * Ndim] = acc[mi][ni][r] * sc + bz;
    }
  }
}

// ============================================================================
// Path B fallback (fused conversion, 128^2) -- unchanged.
// ============================================================================
__device__ __forceinline__ void mfma_tile(const unsigned short* As, const unsigned short* Bs,
                                          int am, int bnl, int quad, f32x4 acc[4][4]) {
#pragma unroll
  for (int ks = 0; ks < 2; ++ks) {
    const int c = ks * 4 + quad;
    bf16x8 af[4], bv[4];
#pragma unroll
    for (int t = 0; t < 4; ++t) {
      int ma = am + t * 16;
      af[t] = *(const bf16x8*)(As + (ma * 8 + (c ^ (ma & 7))) * 8);
      int nb = bnl + t * 16;
      bv[t] = *(const bf16x8*)(Bs + (nb * 8 + (c ^ (nb & 7))) * 8);
    }
#pragma unroll
    for (int mi = 0; mi < 4; ++mi)
#pragma unroll
      for (int ni = 0; ni < 4; ++ni)
        acc[mi][ni] = __builtin_amdgcn_mfma_f32_16x16x32_bf16(af[mi], bv[ni], acc[mi][ni], 0, 0, 0);
  }
}

__device__ __forceinline__ void epilogue128(float* __restrict__ out,
                                            const float* __restrict__ scale,
                                            const float* __restrict__ bias,
                                            int row0, int col0, int wm, int wn, int lane,
                                            f32x4 acc[4][4]) {
  const int rbase = (lane >> 4) * 4;
#pragma unroll
  for (int ni = 0; ni < 4; ++ni) {
    const int n = col0 + wn * 64 + ni * 16 + (lane & 15);
    const float sc = scale[n];
    const float bz = bias[n];
#pragma unroll
    for (int mi = 0; mi < 4; ++mi) {
      const int m = row0 + wm * 64 + mi * 16 + rbase;
      float* o = out + (long)m * Ndim + n;
#pragma unroll
      for (int r = 0; r < 4; ++r)
        o[(long)r * Ndim] = acc[mi][ni][r] * sc + bz;
    }
  }
}

__global__ __launch_bounds__(256, 2) void gemm_fused(const float* __restrict__ X,
                                                     const int* __restrict__ Wq,
                                                     const float* __restrict__ scale,
                                                     const float* __restrict__ bias,
                                                     float* __restrict__ out) {
  __shared__ unsigned short As[BM * BK];
  __shared__ unsigned short Bs[BN * BK];

  const int tid = threadIdx.x;
  const int lane = tid & 63;
  const int w = tid >> 6;
  const int wm = w & 1, wn = w >> 1;
  const int bid = blockIdx.x;
  const int bn = bid % TILES_N;
  const int bm = bid / TILES_N;
  const int row0 = bm * BM, col0 = bn * BN;

  int slot[4];
  long aoff[4], boff[4];
#pragma unroll
  for (int i = 0; i < 4; ++i) {
    int s = i * 256 + tid;
    int m = s >> 3, cs = s & 7, c = cs ^ (m & 7);
    slot[i] = s;
    aoff[i] = (long)(row0 + m) * Kdim + c * 8;
    boff[i] = (long)(col0 + m) * Kdim + c * 8;
  }

  f32x4 acc[4][4];
#pragma unroll
  for (int mi = 0; mi < 4; ++mi)
#pragma unroll
    for (int ni = 0; ni < 4; ++ni) acc[mi][ni] = (f32x4){0.f, 0.f, 0.f, 0.f};

  const int am = wm * 64 + (lane & 15);
  const int bnl = wn * 64 + (lane & 15);
  const int quad = lane >> 4;

  for (int kt = 0; kt < Kdim / BK; ++kt) {
    uint4 aw[4], bw[4];
#pragma unroll
    for (int i = 0; i < 4; ++i) {
      const float4* ap = (const float4*)(X + aoff[i] + kt * BK);
      float4 a0 = ap[0];
      float4 a1 = ap[1];
      aw[i].x = packbf(a0.x, a0.y);
      aw[i].y = packbf(a0.z, a0.w);
      aw[i].z = packbf(a1.x, a1.y);
      aw[i].w = packbf(a1.z, a1.w);
      const int4* bp = (const int4*)(Wq + boff[i] + kt * BK);
      int4 b0 = bp[0];
      int4 b1 = bp[1];
      bw[i].x = i32x2bf(b0.x, b0.y);
      bw[i].y = i32x2bf(b0.z, b0.w);
      bw[i].z = i32x2bf(b1.x, b1.y);
      bw[i].w = i32x2bf(b1.z, b1.w);
    }
    __syncthreads();
#pragma unroll
    for (int i = 0; i < 4; ++i) {
      *(uint4*)(&As[slot[i] * 8]) = aw[i];
      *(uint4*)(&Bs[slot[i] * 8]) = bw[i];
    }
    __syncthreads();
    mfma_tile(As, Bs, am, bnl, quad, acc);
  }
  epilogue128(out, scale, bias, row0, col0, wm, wn, lane, acc);
}

extern "C" void kernel_launch(void* const* d_in, const int* in_sizes, int n_in,
                              void* d_out, int out_size, void* d_ws, size_t ws_size,
                              hipStream_t stream) {
  const float* x = (const float*)d_in[0];
  const int* wq = (const int*)d_in[1];      // int8 weights uploaded as int32 [N*K]
  const float* wscale = (const float*)d_in[2];
  const float* wbias = (const float*)d_in[3];
  float* out = (float*)d_out;

  const size_t needA = ((size_t)Mdim * Kdim + (size_t)Ndim * Kdim) * 2;  // 160 MB bf16
  if (ws_size >= needA) {
    unsigned short* xb = (unsigned short*)d_ws;
    unsigned short* wb = xb + (size_t)Mdim * Kdim;
    cvt_x_kernel<<<(Mdim * Kdim) / 8 / 256, 256, 0, stream>>>((const float4*)x, (uint4*)xb);
    cvt_w_kernel<<<(Ndim / 256) * (Kdim / 8), 256, 0, stream>>>((const int4*)wq, (uint4*)wb);
    gemm_bf16_8ph<<<NWG2, 512, 0, stream>>>(xb, wb, wscale, wbias, out);
  } else {
    gemm_fused<<<TILES_M * TILES_N, 256, 0, stream>>>(x, wq, wscale, wbias, out);
  }
}

// Round 4
// 1177.950 us; speedup vs baseline: 1.3801x; 1.2493x over previous
//
#include <hip/hip_runtime.h>

// ============================================================================
// R4 = R3 resubmit (R3 bench died to infra: "container failed twice", no
// kernel signal; kernel re-audited for deadlock/OOB -- clean).
// R3 theory: R2 still spilled in-loop (arch VGPR pinned at 128 + 128 acc =
// 256/wave cap at 2 waves/SIMD; demand ~270; extra 40MB HBM writes =
// L2-leaked scratch; MfmaUtil 21%). Cut register demand ~48 regs: quadrant
// order (0,0)->(1,0)->(1,1)->(0,1) so bf shrinks to [2][2] (B-pair reloaded
// ph2, A-h0 reloaded ph3). Stage placement re-derived: ph0/ph1 stage tile
// g+1 {A h0, B h1} -> other buf; ph2/ph3 stage tile g+2 {A h1, B h0} ->
// this buf; vmcnt(4) per group. Predict: WRITE_SIZE 328->~290MB (spill
// gone), MfmaUtil 21->45-60%, gemm 1052 -> ~400-470us.
// ============================================================================

static constexpr int Mdim = 4096;
static constexpr int Kdim = 4096;
static constexpr int Ndim = 16384;

// ---- Path B (fallback) geometry ----
static constexpr int BM = 128, BN = 128, BK = 64;
static constexpr int TILES_N = Ndim / BN;  // 128
static constexpr int TILES_M = Mdim / BM;  // 32

// ---- Path A 8-phase geometry ----
static constexpr int BM2 = 256, BN2 = 256, BK2 = 64;
static constexpr int TM2 = Mdim / BM2;   // 16
static constexpr int TN2 = Ndim / BN2;   // 64
static constexpr int NT2 = Kdim / BK2;   // 64 K-tiles
static constexpr int NWG2 = TM2 * TN2;   // 1024 (% 8 == 0 -> simple XCD swizzle)

typedef __attribute__((ext_vector_type(8))) short bf16x8;  // 8 bf16 = 4 VGPRs
typedef __attribute__((ext_vector_type(4))) float f32x4;   // MFMA C/D

// ---------- conversion helpers ----------
__device__ __forceinline__ unsigned packbf(float lo, float hi) {
  unsigned a = __builtin_bit_cast(unsigned, lo);
  unsigned b = __builtin_bit_cast(unsigned, hi);
  a += 0x7FFFu + ((a >> 16) & 1u);
  b += 0x7FFFu + ((b >> 16) & 1u);
  return (a >> 16) | (b & 0xFFFF0000u);
}

__device__ __forceinline__ unsigned i32x2bf(int lo, int hi) {
  float f0 = (float)lo;
  float f1 = (float)hi;
  return (__builtin_bit_cast(unsigned, f0) >> 16) |
         (__builtin_bit_cast(unsigned, f1) & 0xFFFF0000u);
}

// ---------- standalone converters (memory-bound) ----------
__global__ void cvt_x_kernel(const float4* __restrict__ in, uint4* __restrict__ out) {
  int i = blockIdx.x * 256 + threadIdx.x;
  float4 a = in[2 * i];
  float4 b = in[2 * i + 1];
  uint4 o;
  o.x = packbf(a.x, a.y);
  o.y = packbf(a.z, a.w);
  o.z = packbf(b.x, b.y);
  o.w = packbf(b.z, b.w);
  out[i] = o;
}

// harness uploads integer inputs as int32: weight_q is N*K int32 in [-127,127].
__global__ void cvt_w_kernel(const int4* __restrict__ in, uint4* __restrict__ out) {
  int i = blockIdx.x * 256 + threadIdx.x;
  int4 a = in[2 * i];
  int4 b = in[2 * i + 1];
  uint4 o;
  o.x = i32x2bf(a.x, a.y);
  o.y = i32x2bf(a.z, a.w);
  o.z = i32x2bf(b.x, b.y);
  o.w = i32x2bf(b.z, b.w);
  out[i] = o;
}

// ============================================================================
// Path A GEMM: 256x256 tile, BK=64, 8 waves (2M x 4N), 8-phase counted-vmcnt.
//
// Quadrant order per K-tile: (mh0,n01) (mh1,n01) (mh1,n23) (mh0,n23).
//   ph0: LDA h0 (8) + LDB n01 (4) | STG_A(dn,h0,g+1) | bar,lgkm0,MFMA(0,0)
//   ph1: LDA h1 (8)               | STG_B(dn,h1,g+1) | bar,lgkm0,MFMA(4,0)
//   ph2: LDB n23 (4, reuse slots) | STG_A(d ,h1,g+2) | bar,lgkm0,MFMA(4,2)
//   ph3: LDA h0 reload (8)        | STG_B(d ,h0,g+2) | bar,lgkm0,MFMA(0,2),
//                                                      vmcnt(4), bar
// Region safety (reads of buf d: A h0 @ ph0,ph3; A h1 @ ph1; B @ ph0,ph2):
//   - ph0/ph1 stages target buf dn: prev group's reads of dn completed at
//     its lgkm0s before its closing barrier.
//   - ph2 stages A(d,h1): last read ph1, done at ph1 lgkm0 < ph2 issue.
//   - ph3 stages B(d,h0): last read ph2, done at ph2 lgkm0 < ph3 issue.
//   - A(d,h0) re-read at ph3 is never staged this group.
// vmcnt(4): per-wave outstanding at group end <= 12 (prev ph2/ph3 4 + this
// group 8); completes all but the 4 newest -> tile g+1 fully resident; keeps
// this group's ph2/ph3 (tile g+2 {A h1, B h0}) in flight.
// ============================================================================

__global__ __launch_bounds__(512, 2) void gemm_bf16_8ph(
    const unsigned short* __restrict__ A,   // [M,K] bf16
    const unsigned short* __restrict__ B,   // [N,K] bf16
    const float* __restrict__ scale,
    const float* __restrict__ bias,
    float* __restrict__ out) {
  __shared__ unsigned short As[2 * 2 * 1024 * 8];  // 64 KiB
  __shared__ unsigned short Bs[2 * 2 * 1024 * 8];  // 64 KiB

  const int tid = threadIdx.x;
  const int lane = tid & 63;
  const int w = tid >> 6;           // wave 0..7
  const int wm = w >> 2;            // 0..1 -> rows wm*128
  const int wn = w & 3;             // 0..3 -> cols wn*64
  const int l15 = lane & 15;
  const int quad = lane >> 4;
  const int sw = l15 & 7;           // read-side swizzle key
  const int bhalf = wn >> 1;        // this wave's fixed B half

  // T1: bijective XCD swizzle (NWG2 % 8 == 0)
  const int bid = blockIdx.x;
  const int wg = (bid & 7) * (NWG2 / 8) + (bid >> 3);
  const int bm = wg / TN2, bn = wg % TN2;
  const int row0 = bm * BM2, col0 = bn * BN2;

  // Per-thread pre-swizzled global byte offsets for staging, [half][load i].
  unsigned aoff[2][2], boff[2][2];
#pragma unroll
  for (int h = 0; h < 2; ++h)
#pragma unroll
    for (int i = 0; i < 2; ++i) {
      int ch = (w * 2 + i) * 64 + lane;       // chunk within half-tile
      int ir = ch >> 3;                        // inner row 0..127
      int c = (ch & 7) ^ (ir & 7);             // inverse of read swizzle
      int ra = (ir >> 6) * 128 + h * 64 + (ir & 63);  // A tile row
      int rb = h * 128 + ir;                           // B tile row
      aoff[h][i] = (unsigned)((((long)(row0 + ra)) * Kdim + c * 8) * 2);
      boff[h][i] = (unsigned)((((long)(col0 + rb)) * Kdim + c * 8) * 2);
    }

#define STG_A(d, h, kt)                                                                   \
  do {                                                                                    \
    __builtin_amdgcn_global_load_lds(                                                     \
        (const __attribute__((address_space(1))) void*)((const char*)A + aoff[h][0] + (kt)*128), \
        (__attribute__((address_space(3))) void*)(&As[(((d)*2 + (h)) * 1024 + (w*2 + 0) * 64) * 8]), 16, 0, 0); \
    __builtin_amdgcn_global_load_lds(                                                     \
        (const __attribute__((address_space(1))) void*)((const char*)A + aoff[h][1] + (kt)*128), \
        (__attribute__((address_space(3))) void*)(&As[(((d)*2 + (h)) * 1024 + (w*2 + 1) * 64) * 8]), 16, 0, 0); \
  } while (0)

#define STG_B(d, h, kt)                                                                   \
  do {                                                                                    \
    __builtin_amdgcn_global_load_lds(                                                     \
        (const __attribute__((address_space(1))) void*)((const char*)B + boff[h][0] + (kt)*128), \
        (__attribute__((address_space(3))) void*)(&Bs[(((d)*2 + (h)) * 1024 + (w*2 + 0) * 64) * 8]), 16, 0, 0); \
    __builtin_amdgcn_global_load_lds(                                                     \
        (const __attribute__((address_space(1))) void*)((const char*)B + boff[h][1] + (kt)*128), \
        (__attribute__((address_space(3))) void*)(&Bs[(((d)*2 + (h)) * 1024 + (w*2 + 1) * 64) * 8]), 16, 0, 0); \
  } while (0)

// Fragment reads (swizzled). A: half h = m-half, subtile t3 (0..3). B: n-subtile.
#define LDA(dst, d, h, t3, ks)                                                            \
  dst = *(const bf16x8*)(As + ((((d)*2 + (h)) * 1024 + (wm * 64 + (t3) * 16 + l15) * 8 +  \
                                (((ks)*4 + quad) ^ sw)) * 8))
#define LDB(dst, d, n, ks)                                                                \
  dst = *(const bf16x8*)(Bs + ((((d)*2 + bhalf) * 1024 + ((wn & 1) * 64 + (n) * 16 + l15) * 8 + \
                                (((ks)*4 + quad) ^ sw)) * 8))

#define LDA8(d, h)                                                                        \
  _Pragma("unroll") for (int t = 0; t < 4; ++t) {                                         \
    LDA(af[t][0], d, h, t, 0);                                                            \
    LDA(af[t][1], d, h, t, 1);                                                            \
  }

// Loads n-subtiles (n0), (n0)+1 into bf slots 0,1 (slots reused across phases).
#define LDB2(d, n0)                                                                       \
  _Pragma("unroll") for (int n = 0; n < 2; ++n) {                                         \
    LDB(bf[n][0], d, (n0) + n, 0);                                                        \
    LDB(bf[n][1], d, (n0) + n, 1);                                                        \
  }

// 16 MFMAs: acc rows mb..mb+3, cols nb..nb+1, from af[0..3] x bf[0..1].
#define MFMAQ(mb, nb)                                                                     \
  __builtin_amdgcn_s_setprio(1);                                                          \
  _Pragma("unroll") for (int mi = 0; mi < 4; ++mi) {                                      \
    _Pragma("unroll") for (int ni = 0; ni < 2; ++ni) {                                    \
      _Pragma("unroll") for (int ks = 0; ks < 2; ++ks) {                                  \
        acc[(mb) + mi][(nb) + ni] = __builtin_amdgcn_mfma_f32_16x16x32_bf16(              \
            af[mi][ks], bf[ni][ks], acc[(mb) + mi][(nb) + ni], 0, 0, 0);                  \
      }                                                                                   \
    }                                                                                     \
  }                                                                                       \
  __builtin_amdgcn_s_setprio(0);

#define BAR __builtin_amdgcn_s_barrier()
#define LGKM0 asm volatile("s_waitcnt lgkmcnt(0)" ::: "memory")
#define VMC(n) asm volatile("s_waitcnt vmcnt(" #n ")" ::: "memory")

// One K-tile (4 phases). d/dn/S1/S2 MUST be literal constants.
#define GROUP(g, d, dn, S1, S2)              \
  {                                          \
    LDA8(d, 0);                              \
    LDB2(d, 0);                              \
    if (S1) STG_A(dn, 0, (g) + 1);           \
    BAR;                                     \
    LGKM0;                                   \
    MFMAQ(0, 0);                             \
    BAR;                                     \
    LDA8(d, 1);                              \
    if (S1) STG_B(dn, 1, (g) + 1);           \
    BAR;                                     \
    LGKM0;                                   \
    MFMAQ(4, 0);                             \
    BAR;                                     \
    LDB2(d, 2);                              \
    if (S2) STG_A(d, 1, (g) + 2);            \
    BAR;                                     \
    LGKM0;                                   \
    MFMAQ(4, 2);                             \
    BAR;                                     \
    LDA8(d, 0);                              \
    if (S2) STG_B(d, 0, (g) + 2);            \
    BAR;                                     \
    LGKM0;                                   \
    MFMAQ(0, 2);                             \
    VMC(4);                                  \
    BAR;                                     \
  }

  f32x4 acc[8][4];
#pragma unroll
  for (int mi = 0; mi < 8; ++mi)
#pragma unroll
    for (int ni = 0; ni < 4; ++ni) acc[mi][ni] = (f32x4){0.f, 0.f, 0.f, 0.f};

  bf16x8 af[4][2];  // current A m-half (h0 -> h1 -> h0 reload)
  bf16x8 bf[2][2];  // current B n-pair (slots reused: n01 then n23)

  // Prologue: tile0 all 4 halves + tile1 {A h1, B h0} (the steady-state
  // "prev group ph2/ph3" stages). vmcnt(4): tile0 resident, tile1 pair in
  // flight. Tile1's {A h0, B h1} staged by group 0 ph0/ph1.
  STG_A(0, 0, 0);
  STG_A(0, 1, 0);
  STG_B(0, 0, 0);
  STG_B(0, 1, 0);
  STG_A(1, 1, 1);
  STG_B(1, 0, 1);
  VMC(4);
  BAR;

#pragma unroll 1
  for (int g = 0; g < NT2 - 2; g += 2) {
    GROUP(g, 0, 1, 1, 1);
    GROUP(g + 1, 1, 0, 1, 1);
  }
  GROUP(NT2 - 2, 0, 1, 1, 0);
  // Tail: drain everything before the final tile's reads.
  VMC(0);
  BAR;
  GROUP(NT2 - 1, 1, 0, 0, 0);

#undef GROUP
#undef STG_A
#undef STG_B
#undef LDA
#undef LDB
#undef LDA8
#undef LDB2
#undef MFMAQ

  // Epilogue: C/D layout col=lane&15, row=quad*4+reg (m89-verified).
  const int rbase = quad * 4;
#pragma unroll
  for (int ni = 0; ni < 4; ++ni) {
    const int n = col0 + wn * 64 + ni * 16 + l15;
    const float sc = scale[n];
    const float bz = bias[n];
#pragma unroll
    for (int mi = 0; mi < 8; ++mi) {
      const int m = row0 + wm * 128 + mi * 16 + rbase;
      float* o = out + (long)m * Ndim + n;
#pragma unroll
      for (int r = 0; r < 4; ++r) o[(long)r * Ndim] = acc[mi][ni][r] * sc + bz;
    }
  }
}

// ============================================================================
// Path B fallback (fused conversion, 128^2) -- unchanged.
// ============================================================================
__device__ __forceinline__ void mfma_tile(const unsigned short* As, const unsigned short* Bs,
                                          int am, int bnl, int quad, f32x4 acc[4][4]) {
#pragma unroll
  for (int ks = 0; ks < 2; ++ks) {
    const int c = ks * 4 + quad;
    bf16x8 af[4], bv[4];
#pragma unroll
    for (int t = 0; t < 4; ++t) {
      int ma = am + t * 16;
      af[t] = *(const bf16x8*)(As + (ma * 8 + (c ^ (ma & 7))) * 8);
      int nb = bnl + t * 16;
      bv[t] = *(const bf16x8*)(Bs + (nb * 8 + (c ^ (nb & 7))) * 8);
    }
#pragma unroll
    for (int mi = 0; mi < 4; ++mi)
#pragma unroll
      for (int ni = 0; ni < 4; ++ni)
        acc[mi][ni] = __builtin_amdgcn_mfma_f32_16x16x32_bf16(af[mi], bv[ni], acc[mi][ni], 0, 0, 0);
  }
}

__device__ __forceinline__ void epilogue128(float* __restrict__ out,
                                            const float* __restrict__ scale,
                                            const float* __restrict__ bias,
                                            int row0, int col0, int wm, int wn, int lane,
                                            f32x4 acc[4][4]) {
  const int rbase = (lane >> 4) * 4;
#pragma unroll
  for (int ni = 0; ni < 4; ++ni) {
    const int n = col0 + wn * 64 + ni * 16 + (lane & 15);
    const float sc = scale[n];
    const float bz = bias[n];
#pragma unroll
    for (int mi = 0; mi < 4; ++mi) {
      const int m = row0 + wm * 64 + mi * 16 + rbase;
      float* o = out + (long)m * Ndim + n;
#pragma unroll
      for (int r = 0; r < 4; ++r)
        o[(long)r * Ndim] = acc[mi][ni][r] * sc + bz;
    }
  }
}

__global__ __launch_bounds__(256, 2) void gemm_fused(const float* __restrict__ X,
                                                     const int* __restrict__ Wq,
                                                     const float* __restrict__ scale,
                                                     const float* __restrict__ bias,
                                                     float* __restrict__ out) {
  __shared__ unsigned short As[BM * BK];
  __shared__ unsigned short Bs[BN * BK];

  const int tid = threadIdx.x;
  const int lane = tid & 63;
  const int w = tid >> 6;
  const int wm = w & 1, wn = w >> 1;
  const int bid = blockIdx.x;
  const int bn = bid % TILES_N;
  const int bm = bid / TILES_N;
  const int row0 = bm * BM, col0 = bn * BN;

  int slot[4];
  long aoff[4], boff[4];
#pragma unroll
  for (int i = 0; i < 4; ++i) {
    int s = i * 256 + tid;
    int m = s >> 3, cs = s & 7, c = cs ^ (m & 7);
    slot[i] = s;
    aoff[i] = (long)(row0 + m) * Kdim + c * 8;
    boff[i] = (long)(col0 + m) * Kdim + c * 8;
  }

  f32x4 acc[4][4];
#pragma unroll
  for (int mi = 0; mi < 4; ++mi)
#pragma unroll
    for (int ni = 0; ni < 4; ++ni) acc[mi][ni] = (f32x4){0.f, 0.f, 0.f, 0.f};

  const int am = wm * 64 + (lane & 15);
  const int bnl = wn * 64 + (lane & 15);
  const int quad = lane >> 4;

  for (int kt = 0; kt < Kdim / BK; ++kt) {
    uint4 aw[4], bw[4];
#pragma unroll
    for (int i = 0; i < 4; ++i) {
      const float4* ap = (const float4*)(X + aoff[i] + kt * BK);
      float4 a0 = ap[0];
      float4 a1 = ap[1];
      aw[i].x = packbf(a0.x, a0.y);
      aw[i].y = packbf(a0.z, a0.w);
      aw[i].z = packbf(a1.x, a1.y);
      aw[i].w = packbf(a1.z, a1.w);
      const int4* bp = (const int4*)(Wq + boff[i] + kt * BK);
      int4 b0 = bp[0];
      int4 b1 = bp[1];
      bw[i].x = i32x2bf(b0.x, b0.y);
      bw[i].y = i32x2bf(b0.z, b0.w);
      bw[i].z = i32x2bf(b1.x, b1.y);
      bw[i].w = i32x2bf(b1.z, b1.w);
    }
    __syncthreads();
#pragma unroll
    for (int i = 0; i < 4; ++i) {
      *(uint4*)(&As[slot[i] * 8]) = aw[i];
      *(uint4*)(&Bs[slot[i] * 8]) = bw[i];
    }
    __syncthreads();
    mfma_tile(As, Bs, am, bnl, quad, acc);
  }
  epilogue128(out, scale, bias, row0, col0, wm, wn, lane, acc);
}

extern "C" void kernel_launch(void* const* d_in, const int* in_sizes, int n_in,
                              void* d_out, int out_size, void* d_ws, size_t ws_size,
                              hipStream_t stream) {
  const float* x = (const float*)d_in[0];
  const int* wq = (const int*)d_in[1];      // int8 weights uploaded as int32 [N*K]
  const float* wscale = (const float*)d_in[2];
  const float* wbias = (const float*)d_in[3];
  float* out = (float*)d_out;

  const size_t needA = ((size_t)Mdim * Kdim + (size_t)Ndim * Kdim) * 2;  // 160 MB bf16
  if (ws_size >= needA) {
    unsigned short* xb = (unsigned short*)d_ws;
    unsigned short* wb = xb + (size_t)Mdim * Kdim;
    cvt_x_kernel<<<(Mdim * Kdim) / 8 / 256, 256, 0, stream>>>((const float4*)x, (uint4*)xb);
    cvt_w_kernel<<<(Ndim / 256) * (Kdim / 8), 256, 0, stream>>>((const int4*)wq, (uint4*)wb);
    gemm_bf16_8ph<<<NWG2, 512, 0, stream>>>(xb, wb, wscale, wbias, out);
  } else {
    gemm_fused<<<TILES_M * TILES_N, 256, 0, stream>>>(x, wq, wscale, wbias, out);
  }
}

// Round 5
// 1091.196 us; speedup vs baseline: 1.4898x; 1.0795x over previous
//
#include <hip/hip_runtime.h>

// ============================================================================
// R5 theory: R2->R4 register-relief dose-response (1052->780us) says pressure
// is the wall, but VGPR pinned at 128 + WRITE_SIZE 336MB (output 268) says
// acc placement never verified -> force acc into AGPRs with inline-asm MFMA
// ("+a" C/D), ks-outer order (break back-to-back acc dependency), and a
// cheaper quadrant order (28 ds_reads/K-tile, B-pair reload instead of
// A-half reload). Schedule family unchanged (4-phase counted-vmcnt).
// Predict: VGPR <=110, WRITE_SIZE ~290MB, MfmaUtil 45-60%, gemm ~420-520us.
// ============================================================================

static constexpr int Mdim = 4096;
static constexpr int Kdim = 4096;
static constexpr int Ndim = 16384;

// ---- Path B (fallback) geometry ----
static constexpr int BM = 128, BN = 128, BK = 64;
static constexpr int TILES_N = Ndim / BN;  // 128
static constexpr int TILES_M = Mdim / BM;  // 32

// ---- Path A 8-phase geometry ----
static constexpr int BM2 = 256, BN2 = 256, BK2 = 64;
static constexpr int TM2 = Mdim / BM2;   // 16
static constexpr int TN2 = Ndim / BN2;   // 64
static constexpr int NT2 = Kdim / BK2;   // 64 K-tiles
static constexpr int NWG2 = TM2 * TN2;   // 1024 (% 8 == 0 -> simple XCD swizzle)

typedef __attribute__((ext_vector_type(8))) short bf16x8;  // 8 bf16 = 4 VGPRs
typedef __attribute__((ext_vector_type(4))) float f32x4;   // MFMA C/D

// ---------- conversion helpers ----------
__device__ __forceinline__ unsigned packbf(float lo, float hi) {
  unsigned a = __builtin_bit_cast(unsigned, lo);
  unsigned b = __builtin_bit_cast(unsigned, hi);
  a += 0x7FFFu + ((a >> 16) & 1u);
  b += 0x7FFFu + ((b >> 16) & 1u);
  return (a >> 16) | (b & 0xFFFF0000u);
}

__device__ __forceinline__ unsigned i32x2bf(int lo, int hi) {
  float f0 = (float)lo;
  float f1 = (float)hi;
  return (__builtin_bit_cast(unsigned, f0) >> 16) |
         (__builtin_bit_cast(unsigned, f1) & 0xFFFF0000u);
}

// ---------- standalone converters (memory-bound) ----------
__global__ void cvt_x_kernel(const float4* __restrict__ in, uint4* __restrict__ out) {
  int i = blockIdx.x * 256 + threadIdx.x;
  float4 a = in[2 * i];
  float4 b = in[2 * i + 1];
  uint4 o;
  o.x = packbf(a.x, a.y);
  o.y = packbf(a.z, a.w);
  o.z = packbf(b.x, b.y);
  o.w = packbf(b.z, b.w);
  out[i] = o;
}

// harness uploads integer inputs as int32: weight_q is N*K int32 in [-127,127].
__global__ void cvt_w_kernel(const int4* __restrict__ in, uint4* __restrict__ out) {
  int i = blockIdx.x * 256 + threadIdx.x;
  int4 a = in[2 * i];
  int4 b = in[2 * i + 1];
  uint4 o;
  o.x = i32x2bf(a.x, a.y);
  o.y = i32x2bf(a.z, a.w);
  o.z = i32x2bf(b.x, b.y);
  o.w = i32x2bf(b.z, b.w);
  out[i] = o;
}

// ============================================================================
// Path A GEMM: 256x256 tile, BK=64, 8 waves (2M x 4N), 4-phase counted-vmcnt.
//
// Quadrant order per K-tile g (buf d): (mh0,n01) (mh0,n23) (mh1,n23) (mh1,n01).
//   ph0: LDA8 h0 + LDB2 n01 (12 rd) |                      | bar,lgkm0,MFMA(0,0)
//   ph1: LDB2 n23 (4 rd)            | STG_B(dn,h0+h1,g+1)  | bar,lgkm0,MFMA(0,2)
//   ph2: LDA8 h1 (8 rd)             | STG_A(d, h0, g+2)    | bar,lgkm0,MFMA(4,2)
//   ph3: LDB2 n01 reload (4 rd)     | STG_A(d, h1, g+2)    | bar,lgkm0,MFMA(4,0)
//                                                          | vmcnt(4), bar
// WAR safety (LDS reads of buf d: A h0 @ph0, A h1 @ph2, B @ph0,ph1,ph3):
//   - ph1 stage -> dn: prev group's last read of dn drained at its ph3 lgkm0.
//   - ph2 stages A(d,h0): last read ph0, drained at ph0 lgkm0.
//   - ph3 stages A(d,h1): last read ph2, drained at ph2 lgkm0.
//   - B(d) regions are never staged during a group that reads them.
// vmcnt(4): outstanding at group end = prev ph2/ph3 A(d,*,g+1)... in steady
// state = 12 calls; completing all but 4 lands tile g+1 fully (A staged 2
// groups back, B staged this ph1), keeps this ph2/ph3 A(*,g+2) in flight.
// ============================================================================

__global__ __launch_bounds__(512, 2) void gemm_bf16_8ph(
    const unsigned short* __restrict__ A,   // [M,K] bf16
    const unsigned short* __restrict__ B,   // [N,K] bf16
    const float* __restrict__ scale,
    const float* __restrict__ bias,
    float* __restrict__ out) {
  __shared__ unsigned short As[2 * 2 * 1024 * 8];  // 64 KiB
  __shared__ unsigned short Bs[2 * 2 * 1024 * 8];  // 64 KiB

  const int tid = threadIdx.x;
  const int lane = tid & 63;
  const int w = tid >> 6;           // wave 0..7
  const int wm = w >> 2;            // 0..1 -> rows wm*128
  const int wn = w & 3;             // 0..3 -> cols wn*64
  const int l15 = lane & 15;
  const int quad = lane >> 4;
  const int sw = l15 & 7;           // read-side swizzle key
  const int bhalf = wn >> 1;        // this wave's fixed B half

  // T1: bijective XCD swizzle (NWG2 % 8 == 0)
  const int bid = blockIdx.x;
  const int wg = (bid & 7) * (NWG2 / 8) + (bid >> 3);
  const int bm = wg / TN2, bn = wg % TN2;
  const int row0 = bm * BM2, col0 = bn * BN2;

  // Per-thread pre-swizzled global byte offsets for staging, [half][load i].
  unsigned aoff[2][2], boff[2][2];
#pragma unroll
  for (int h = 0; h < 2; ++h)
#pragma unroll
    for (int i = 0; i < 2; ++i) {
      int ch = (w * 2 + i) * 64 + lane;       // chunk within half-tile
      int ir = ch >> 3;                        // inner row 0..127
      int c = (ch & 7) ^ (ir & 7);             // inverse of read swizzle
      int ra = (ir >> 6) * 128 + h * 64 + (ir & 63);  // A tile row
      int rb = h * 128 + ir;                           // B tile row
      aoff[h][i] = (unsigned)((((long)(row0 + ra)) * Kdim + c * 8) * 2);
      boff[h][i] = (unsigned)((((long)(col0 + rb)) * Kdim + c * 8) * 2);
    }

#define STG_A(d, h, kt)                                                                   \
  do {                                                                                    \
    __builtin_amdgcn_global_load_lds(                                                     \
        (const __attribute__((address_space(1))) void*)((const char*)A + aoff[h][0] + (kt)*128), \
        (__attribute__((address_space(3))) void*)(&As[(((d)*2 + (h)) * 1024 + (w*2 + 0) * 64) * 8]), 16, 0, 0); \
    __builtin_amdgcn_global_load_lds(                                                     \
        (const __attribute__((address_space(1))) void*)((const char*)A + aoff[h][1] + (kt)*128), \
        (__attribute__((address_space(3))) void*)(&As[(((d)*2 + (h)) * 1024 + (w*2 + 1) * 64) * 8]), 16, 0, 0); \
  } while (0)

#define STG_B(d, h, kt)                                                                   \
  do {                                                                                    \
    __builtin_amdgcn_global_load_lds(                                                     \
        (const __attribute__((address_space(1))) void*)((const char*)B + boff[h][0] + (kt)*128), \
        (__attribute__((address_space(3))) void*)(&Bs[(((d)*2 + (h)) * 1024 + (w*2 + 0) * 64) * 8]), 16, 0, 0); \
    __builtin_amdgcn_global_load_lds(                                                     \
        (const __attribute__((address_space(1))) void*)((const char*)B + boff[h][1] + (kt)*128), \
        (__attribute__((address_space(3))) void*)(&Bs[(((d)*2 + (h)) * 1024 + (w*2 + 1) * 64) * 8]), 16, 0, 0); \
  } while (0)

// Fragment reads (swizzled). A: half h = m-half, subtile t3 (0..3). B: n-subtile.
#define LDA(dst, d, h, t3, ks)                                                            \
  dst = *(const bf16x8*)(As + ((((d)*2 + (h)) * 1024 + (wm * 64 + (t3) * 16 + l15) * 8 +  \
                                (((ks)*4 + quad) ^ sw)) * 8))
#define LDB(dst, d, n, ks)                                                                \
  dst = *(const bf16x8*)(Bs + ((((d)*2 + bhalf) * 1024 + ((wn & 1) * 64 + (n) * 16 + l15) * 8 + \
                                (((ks)*4 + quad) ^ sw)) * 8))

#define LDA8(d, h)                                                                        \
  _Pragma("unroll") for (int t = 0; t < 4; ++t) {                                         \
    LDA(af[t][0], d, h, t, 0);                                                            \
    LDA(af[t][1], d, h, t, 1);                                                            \
  }

// Loads n-subtiles (n0), (n0)+1 into bf slots 0,1 (slots reused across phases).
#define LDB2(d, n0)                                                                       \
  _Pragma("unroll") for (int n = 0; n < 2; ++n) {                                         \
    LDB(bf[n][0], d, (n0) + n, 0);                                                        \
    LDB(bf[n][1], d, (n0) + n, 1);                                                        \
  }

// 16 MFMAs, ks OUTER (dependent acc reuses 8 ops apart). Inline asm with "+a"
// pins C/D to AGPRs (decisive register-placement fix). A/B stay "v"; backend
// waitcnt pass still tracks the C++ ds_read -> operand deps.
#define MFMAQ(mb, nb)                                                                     \
  __builtin_amdgcn_s_setprio(1);                                                          \
  _Pragma("unroll") for (int ks = 0; ks < 2; ++ks) {                                      \
    _Pragma("unroll") for (int mi = 0; mi < 4; ++mi) {                                    \
      _Pragma("unroll") for (int ni = 0; ni < 2; ++ni) {                                  \
        asm("v_mfma_f32_16x16x32_bf16 %0, %1, %2, %0"                                     \
            : "+a"(acc[(mb) + mi][(nb) + ni])                                             \
            : "v"(af[mi][ks]), "v"(bf[ni][ks]));                                          \
      }                                                                                   \
    }                                                                                     \
  }                                                                                       \
  __builtin_amdgcn_s_setprio(0);

#define BAR __builtin_amdgcn_s_barrier()
#define LGKM0 asm volatile("s_waitcnt lgkmcnt(0)" ::: "memory")
#define VMC(n) asm volatile("s_waitcnt vmcnt(" #n ")" ::: "memory")

// One K-tile (4 phases). d/dn/SB/SA/V MUST be literal constants.
#define GROUP(g, d, dn, SB, SA, V)           \
  {                                          \
    LDA8(d, 0);                              \
    LDB2(d, 0);                              \
    BAR;                                     \
    LGKM0;                                   \
    MFMAQ(0, 0);                             \
    BAR;                                     \
    LDB2(d, 2);                              \
    if (SB) {                                \
      STG_B(dn, 0, (g) + 1);                 \
      STG_B(dn, 1, (g) + 1);                 \
    }                                        \
    BAR;                                     \
    LGKM0;                                   \
    MFMAQ(0, 2);                             \
    BAR;                                     \
    LDA8(d, 1);                              \
    if (SA) STG_A(d, 0, (g) + 2);            \
    BAR;                                     \
    LGKM0;                                   \
    MFMAQ(4, 2);                             \
    BAR;                                     \
    LDB2(d, 0);                              \
    if (SA) STG_A(d, 1, (g) + 2);            \
    BAR;                                     \
    LGKM0;                                   \
    MFMAQ(4, 0);                             \
    VMC(V);                                  \
    BAR;                                     \
  }

  f32x4 acc[8][4];
#pragma unroll
  for (int mi = 0; mi < 8; ++mi)
#pragma unroll
    for (int ni = 0; ni < 4; ++ni) acc[mi][ni] = (f32x4){0.f, 0.f, 0.f, 0.f};

  bf16x8 af[4][2];  // current A m-half
  bf16x8 bf[2][2];  // current B n-pair (n01 -> n23 -> n01 reload)

  // Prologue: tile0 all 4 units into buf0 + tile1's A units into buf1
  // (mimics steady-state "prev group ph2/ph3"). vmcnt(4): tile0 resident,
  // A(1,*,1) in flight. B(1,*,1) staged by group 0 ph1.
  STG_A(0, 0, 0);
  STG_A(0, 1, 0);
  STG_B(0, 0, 0);
  STG_B(0, 1, 0);
  STG_A(1, 0, 1);
  STG_A(1, 1, 1);
  VMC(4);
  BAR;

#pragma unroll 1
  for (int g = 0; g < NT2 - 2; g += 2) {
    GROUP(g, 0, 1, 1, 1, 4);
    GROUP(g + 1, 1, 0, 1, 1, 4);
  }
  // Tile NT2-2: stage only B(dn,*,NT2-1); drain fully so it's resident.
  GROUP(NT2 - 2, 0, 1, 1, 0, 0);
  // Tile NT2-1: no stages; vmcnt(0) is a no-op.
  GROUP(NT2 - 1, 1, 0, 0, 0, 0);

#undef GROUP
#undef STG_A
#undef STG_B
#undef LDA
#undef LDB
#undef LDA8
#undef LDB2
#undef MFMAQ

  // Epilogue: C/D layout col=lane&15, row=quad*4+reg (m89-verified).
  const int rbase = quad * 4;
#pragma unroll
  for (int ni = 0; ni < 4; ++ni) {
    const int n = col0 + wn * 64 + ni * 16 + l15;
    const float sc = scale[n];
    const float bz = bias[n];
#pragma unroll
    for (int mi = 0; mi < 8; ++mi) {
      const int m = row0 + wm * 128 + mi * 16 + rbase;
      float* o = out + (long)m * Ndim + n;
#pragma unroll
      for (int r = 0; r < 4; ++r) o[(long)r * Ndim] = acc[mi][ni][r] * sc + bz;
    }
  }
}

// ============================================================================
// Path B fallback (fused conversion, 128^2) -- unchanged.
// ============================================================================
__device__ __forceinline__ void mfma_tile(const unsigned short* As, const unsigned short* Bs,
                                          int am, int bnl, int quad, f32x4 acc[4][4]) {
#pragma unroll
  for (int ks = 0; ks < 2; ++ks) {
    const int c = ks * 4 + quad;
    bf16x8 af[4], bv[4];
#pragma unroll
    for (int t = 0; t < 4; ++t) {
      int ma = am + t * 16;
      af[t] = *(const bf16x8*)(As + (ma * 8 + (c ^ (ma & 7))) * 8);
      int nb = bnl + t * 16;
      bv[t] = *(const bf16x8*)(Bs + (nb * 8 + (c ^ (nb & 7))) * 8);
    }
#pragma unroll
    for (int mi = 0; mi < 4; ++mi)
#pragma unroll
      for (int ni = 0; ni < 4; ++ni)
        acc[mi][ni] = __builtin_amdgcn_mfma_f32_16x16x32_bf16(af[mi], bv[ni], acc[mi][ni], 0, 0, 0);
  }
}

__device__ __forceinline__ void epilogue128(float* __restrict__ out,
                                            const float* __restrict__ scale,
                                            const float* __restrict__ bias,
                                            int row0, int col0, int wm, int wn, int lane,
                                            f32x4 acc[4][4]) {
  const int rbase = (lane >> 4) * 4;
#pragma unroll
  for (int ni = 0; ni < 4; ++ni) {
    const int n = col0 + wn * 64 + ni * 16 + (lane & 15);
    const float sc = scale[n];
    const float bz = bias[n];
#pragma unroll
    for (int mi = 0; mi < 4; ++mi) {
      const int m = row0 + wm * 64 + mi * 16 + rbase;
      float* o = out + (long)m * Ndim + n;
#pragma unroll
      for (int r = 0; r < 4; ++r)
        o[(long)r * Ndim] = acc[mi][ni][r] * sc + bz;
    }
  }
}

__global__ __launch_bounds__(256, 2) void gemm_fused(const float* __restrict__ X,
                                                     const int* __restrict__ Wq,
                                                     const float* __restrict__ scale,
                                                     const float* __restrict__ bias,
                                                     float* __restrict__ out) {
  __shared__ unsigned short As[BM * BK];
  __shared__ unsigned short Bs[BN * BK];

  const int tid = threadIdx.x;
  const int lane = tid & 63;
  const int w = tid >> 6;
  const int wm = w & 1, wn = w >> 1;
  const int bid = blockIdx.x;
  const int bn = bid % TILES_N;
  const int bm = bid / TILES_N;
  const int row0 = bm * BM, col0 = bn * BN;

  int slot[4];
  long aoff[4], boff[4];
#pragma unroll
  for (int i = 0; i < 4; ++i) {
    int s = i * 256 + tid;
    int m = s >> 3, cs = s & 7, c = cs ^ (m & 7);
    slot[i] = s;
    aoff[i] = (long)(row0 + m) * Kdim + c * 8;
    boff[i] = (long)(col0 + m) * Kdim + c * 8;
  }

  f32x4 acc[4][4];
#pragma unroll
  for (int mi = 0; mi < 4; ++mi)
#pragma unroll
    for (int ni = 0; ni < 4; ++ni) acc[mi][ni] = (f32x4){0.f, 0.f, 0.f, 0.f};

  const int am = wm * 64 + (lane & 15);
  const int bnl = wn * 64 + (lane & 15);
  const int quad = lane >> 4;

  for (int kt = 0; kt < Kdim / BK; ++kt) {
    uint4 aw[4], bw[4];
#pragma unroll
    for (int i = 0; i < 4; ++i) {
      const float4* ap = (const float4*)(X + aoff[i] + kt * BK);
      float4 a0 = ap[0];
      float4 a1 = ap[1];
      aw[i].x = packbf(a0.x, a0.y);
      aw[i].y = packbf(a0.z, a0.w);
      aw[i].z = packbf(a1.x, a1.y);
      aw[i].w = packbf(a1.z, a1.w);
      const int4* bp = (const int4*)(Wq + boff[i] + kt * BK);
      int4 b0 = bp[0];
      int4 b1 = bp[1];
      bw[i].x = i32x2bf(b0.x, b0.y);
      bw[i].y = i32x2bf(b0.z, b0.w);
      bw[i].z = i32x2bf(b1.x, b1.y);
      bw[i].w = i32x2bf(b1.z, b1.w);
    }
    __syncthreads();
#pragma unroll
    for (int i = 0; i < 4; ++i) {
      *(uint4*)(&As[slot[i] * 8]) = aw[i];
      *(uint4*)(&Bs[slot[i] * 8]) = bw[i];
    }
    __syncthreads();
    mfma_tile(As, Bs, am, bnl, quad, acc);
  }
  epilogue128(out, scale, bias, row0, col0, wm, wn, lane, acc);
}

extern "C" void kernel_launch(void* const* d_in, const int* in_sizes, int n_in,
                              void* d_out, int out_size, void* d_ws, size_t ws_size,
                              hipStream_t stream) {
  const float* x = (const float*)d_in[0];
  const int* wq = (const int*)d_in[1];      // int8 weights uploaded as int32 [N*K]
  const float* wscale = (const float*)d_in[2];
  const float* wbias = (const float*)d_in[3];
  float* out = (float*)d_out;

  const size_t needA = ((size_t)Mdim * Kdim + (size_t)Ndim * Kdim) * 2;  // 160 MB bf16
  if (ws_size >= needA) {
    unsigned short* xb = (unsigned short*)d_ws;
    unsigned short* wb = xb + (size_t)Mdim * Kdim;
    cvt_x_kernel<<<(Mdim * Kdim) / 8 / 256, 256, 0, stream>>>((const float4*)x, (uint4*)xb);
    cvt_w_kernel<<<(Ndim / 256) * (Kdim / 8), 256, 0, stream>>>((const int4*)wq, (uint4*)wb);
    gemm_bf16_8ph<<<NWG2, 512, 0, stream>>>(xb, wb, wscale, wbias, out);
  } else {
    gemm_fused<<<TILES_M * TILES_N, 256, 0, stream>>>(x, wq, wscale, wbias, out);
  }
}